// Round 1
// baseline (115.474 us; speedup 1.0000x reference)
//
#include <hip/hip_runtime.h>
#include <math.h>

// Problem sizes (fixed by reference setup_inputs)
#define BATCH 8
#define NPTS  8192   // pred/full points per batch
#define PPTS  2048   // partial points per batch
#define DLAT  512    // latent dim

typedef __attribute__((ext_vector_type(8)))  short short8;    // 8 bf16 (4 VGPR)
typedef __attribute__((ext_vector_type(16))) float floatx16;  // MFMA 32x32 C/D

// Workspace (float elements):
//   [0..4)    acc: sum_pf, sum_fp, sum_fid, sum_kl   (zeroed by minpass blk 0)
//   [4]       uint completion counter                 (zeroed by minpass blk 0)
//   [8..)     YSPLIT segments of partial min-d^2, each SEG floats
//             (pf | fp | fid regions). Block-owned plain stores, no init.
#define SEG      (2 * BATCH * NPTS + BATCH * PPTS)   // 147456
#define DIR_PF   0
#define DIR_FP   (BATCH * NPTS)
#define DIR_FID  (2 * BATCH * NPTS)
#define OFF_SEG  8

#define CHUNK  512   // y staged per LDS pass
#define XBLK   512   // x points per block (4 waves x 4 col-groups of 32)

__device__ __forceinline__ unsigned short f2bf(float f) {  // RNE float->bf16
    unsigned int u = __float_as_uint(f);
    return (unsigned short)((u + 0x7FFFu + ((u >> 16) & 1u)) >> 16);
}
__device__ __forceinline__ float bf2f(unsigned short s) {
    return __uint_as_float(((unsigned int)s) << 16);
}

// 3-input min in one VALU op. hipcc does NOT fuse fminf chains to v_min3_f32
// here (VALUBusy evidence: ~19.7us busy == plain-v_min count). Force it.
__device__ __forceinline__ float min3f(float a, float b, float c) {
    float d;
    asm("v_min3_f32 %0, %1, %2, %3" : "=v"(d) : "v"(a), "v"(b), "v"(c));
    return d;
}

// min over 16 accumulator regs (16 rows of this lane's column) + carry-in.
// 8 x v_min3_f32, depth 3 (was 16 x v_min_f32).
__device__ __forceinline__ float min16(floatx16 d, float prev) {
    const float a0 = min3f(d[0],  d[1],  d[2]);
    const float a1 = min3f(d[3],  d[4],  d[5]);
    const float a2 = min3f(d[6],  d[7],  d[8]);
    const float a3 = min3f(d[9],  d[10], d[11]);
    const float a4 = min3f(d[12], d[13], d[14]);
    const float b0 = min3f(a0, a1, a2);
    const float b1 = min3f(a3, a4, d[15]);
    return min3f(b0, b1, prev);
}

// Encode one y point + its norm into two uint4 k-half records.
__device__ __forceinline__ void encodeY(float y0, float y1, float y2,
                                        uint4* r0, uint4* r1) {
    const unsigned short h0 = f2bf(y0), h1 = f2bf(y1), h2 = f2bf(y2);
    const unsigned short l0 = f2bf(y0 - bf2f(h0));
    const unsigned short l1 = f2bf(y1 - bf2f(h1));
    const unsigned short l2 = f2bf(y2 - bf2f(h2));
    const float yn = fmaf(y0, y0, fmaf(y1, y1, y2 * y2));
    const unsigned short nh = f2bf(yn);
    const unsigned short nl = f2bf(yn - bf2f(nh));
    r0->x = (unsigned int)h0 | ((unsigned int)h1 << 16);  // k0,k1: yh.x,yh.y
    r0->y = (unsigned int)h2 | ((unsigned int)l0 << 16);  // k2,k3: yh.z,yl.x
    r0->z = (unsigned int)l1 | ((unsigned int)l2 << 16);  // k4,k5: yl.y,yl.z
    r0->w = (unsigned int)h0 | ((unsigned int)h1 << 16);  // k6,k7: yh.x,yh.y
    r1->x = (unsigned int)h2 | ((unsigned int)nh << 16);  // k8,k9: yh.z,yn_h
    r1->y = (unsigned int)nl;                             // k10, k11=0
    r1->z = 0u; r1->w = 0u;
}

// ---------------------------------------------------------------- min pass
// K-slot scheme (11 of 16 used):
//   A(y): k0-2 yh | k3-5 yl | k6-8 yh | k9 yn_h | k10 yn_l | rest 0
//   B(x): k0-2 -2xh | k3-5 -2xh | k6-8 -2xl | k9 1 | k10 1 | rest 0
//   => T = |y|^2 - 2 x.y (split residual ~1e-4); |x|^2 added post-min in fp32.
// Block = 256 thr = 4 waves; block owns 512 x; wave owns 128 x (4 col-groups).
// LDS = sY only (16 KB): x records are encoded per-lane directly into
// registers from global (each lane needs exactly 4 x points), so up to 8
// blocks/CU co-resident (grid is ~4.5 blocks/CU -> fully resident).
__global__ __launch_bounds__(256, 4) void minpass_kernel(
        const float* __restrict__ pred,
        const float* __restrict__ full,
        const float* __restrict__ partial,
        float* __restrict__ wsf,
        int ysplit) {
    const int bid = blockIdx.x;          // 8 batches * 36 subs * ysplit
    const int ys  = bid % ysplit;
    const int r   = bid / ysplit;
    const int b   = r / 36;
    const int s   = r % 36;
    const int yhalf = NPTS / ysplit;

    const int t = threadIdx.x;

    // block 0 zeroes acc + counter for the reduce kernel (stream ordering)
    if (bid == 0) {
        if (t < 4) wsf[t] = 0.0f;
        if (t == 4) ((unsigned int*)wsf)[4] = 0u;
    }

    const float* xset; const float* yset; int minoff; int xbase;
    if (s < 16)      { xset = pred;    yset = full; xbase = b*NPTS + s*XBLK;
                       minoff = OFF_SEG + ys*SEG + DIR_PF  + b*NPTS + s*XBLK; }
    else if (s < 32) { xset = full;    yset = pred; xbase = b*NPTS + (s-16)*XBLK;
                       minoff = OFF_SEG + ys*SEG + DIR_FP  + b*NPTS + (s-16)*XBLK; }
    else             { xset = partial; yset = pred; xbase = b*PPTS + (s-32)*XBLK;
                       minoff = OFF_SEG + ys*SEG + DIR_FID + b*PPTS + (s-32)*XBLK; }

    const int lane = t & 63;
    const int wid  = t >> 6;
    const int l31  = lane & 31;
    const int half = lane >> 5;

    __shared__ uint4 sY[2][CHUNK];   // y records [k-half][point]  (16 KB)

    // ---- per-lane x encode: lane needs x points xw + {0,32,64,96} + l31,
    // and only the k-half record matching its lane half. Encode in registers.
    const int xw = wid * 128;
    short8 bf0, bf1, bf2, bf3;
    float  xn0, xn1, xn2, xn3;
#pragma unroll
    for (int k = 0; k < 4; ++k) {
        const float* xp = xset + (size_t)(xbase + xw + k * 32 + l31) * 3;
        const float x0 = xp[0], x1 = xp[1], x2 = xp[2];
        const float m0 = -2.0f*x0, m1 = -2.0f*x1, m2 = -2.0f*x2;
        const unsigned short h0 = f2bf(m0), h1 = f2bf(m1), h2 = f2bf(m2);
        const unsigned short l0 = f2bf(m0 - bf2f(h0));
        const unsigned short l1 = f2bf(m1 - bf2f(h1));
        const unsigned short l2 = f2bf(m2 - bf2f(h2));
        const unsigned int one = 0x3F80u;
        uint4 r0, r1;
        r0.x = (unsigned int)h0 | ((unsigned int)h1 << 16);  // k0,k1
        r0.y = (unsigned int)h2 | ((unsigned int)h0 << 16);  // k2,k3
        r0.z = (unsigned int)h1 | ((unsigned int)h2 << 16);  // k4,k5
        r0.w = (unsigned int)l0 | ((unsigned int)l1 << 16);  // k6,k7
        r1.x = (unsigned int)l2 | (one << 16);               // k8,k9
        r1.y = one;                                          // k10,k11=0
        r1.z = 0u; r1.w = 0u;
        const uint4 rec = half ? r1 : r0;
        const short8 bfv = *(const short8*)&rec;
        const float  xnv = fmaf(x0, x0, fmaf(x1, x1, x2 * x2));
        if (k == 0) { bf0 = bfv; xn0 = xnv; }
        else if (k == 1) { bf1 = bfv; xn1 = xnv; }
        else if (k == 2) { bf2 = bfv; xn2 = xnv; }
        else { bf3 = bfv; xn3 = xnv; }
    }

    const floatx16 zc = {0,0,0,0, 0,0,0,0, 0,0,0,0, 0,0,0,0};
    float cmin0 = 3.4e38f, cmin1 = 3.4e38f, cmin2 = 3.4e38f, cmin3 = 3.4e38f;

    const float* ypts = yset + (size_t)(b * NPTS + ys * yhalf) * 3;

    for (int c = 0; c < yhalf; c += CHUNK) {
        __syncthreads();  // protect sY reuse
        // stage: thread t encodes chunk points t and t+256 (16B-stride writes)
        for (int i = t; i < CHUNK; i += 256) {
            const float* yp = ypts + (size_t)(c + i) * 3;
            uint4 r0, r1;
            encodeY(yp[0], yp[1], yp[2], &r0, &r1);
            sY[0][i] = r0; sY[1][i] = r1;
        }
        __syncthreads();

        const uint4* sYh = &sY[half][0];
        short8 af = *(const short8*)&sYh[l31];
#pragma unroll
        for (int j = 0; j < CHUNK / 32; ++j) {
            short8 afn = af;
            if (j + 1 < CHUNK / 32)                    // static under unroll
                afn = *(const short8*)&sYh[(j + 1) * 32 + l31];
            // staggered: keep <=2 accumulators live, overlap MFMA with min tree
            const floatx16 d0 = __builtin_amdgcn_mfma_f32_32x32x16_bf16(af, bf0, zc, 0, 0, 0);
            const floatx16 d1 = __builtin_amdgcn_mfma_f32_32x32x16_bf16(af, bf1, zc, 0, 0, 0);
            cmin0 = min16(d0, cmin0);
            const floatx16 d2 = __builtin_amdgcn_mfma_f32_32x32x16_bf16(af, bf2, zc, 0, 0, 0);
            cmin1 = min16(d1, cmin1);
            const floatx16 d3 = __builtin_amdgcn_mfma_f32_32x32x16_bf16(af, bf3, zc, 0, 0, 0);
            cmin2 = min16(d2, cmin2);
            cmin3 = min16(d3, cmin3);
            af = afn;
        }
    }

    // merge the two lane-halves (same column, different row halves), add |x|^2
    const float m0 = fminf(cmin0, __shfl_xor(cmin0, 32, 64));
    const float m1 = fminf(cmin1, __shfl_xor(cmin1, 32, 64));
    const float m2 = fminf(cmin2, __shfl_xor(cmin2, 32, 64));
    const float m3 = fminf(cmin3, __shfl_xor(cmin3, 32, 64));
    if (lane < 32) {
        wsf[minoff + xw + l31]      = fmaxf(m0 + xn0, 0.0f);
        wsf[minoff + xw + 32 + l31] = fmaxf(m1 + xn1, 0.0f);
        wsf[minoff + xw + 64 + l31] = fmaxf(m2 + xn2, 0.0f);
        wsf[minoff + xw + 96 + l31] = fmaxf(m3 + xn3, 0.0f);
    }
}

// ---------------------------------------------------------------- reductions
__device__ __forceinline__ float waveReduceSum(float v) {
#pragma unroll
    for (int o = 32; o > 0; o >>= 1) v += __shfl_down(v, o, 64);
    return v;
}

__device__ __forceinline__ float blockReduceSum(float v) {
    __shared__ float wsum[4];
    const int lane = threadIdx.x & 63;
    const int wid  = threadIdx.x >> 6;
    v = waveReduceSum(v);
    if (lane == 0) wsum[wid] = v;
    __syncthreads();
    if (wid == 0) {
        v = (lane < ((int)blockDim.x >> 6)) ? wsum[lane] : 0.0f;
        v = waveReduceSum(v);
    }
    return v;
}

// Blocks 0..255: pf (256 slots each), 256..511: fp, 512..575: fid, 576: kl.
// (4x more blocks than before: the reduce is latency-bound on a tiny grid.)
#define NRED_BLOCKS 577
__global__ __launch_bounds__(256) void reduce_finalize_kernel(
        float* __restrict__ wsf,
        const float* __restrict__ mu,
        const float* __restrict__ logvar,
        float* __restrict__ out,
        int ysplit) {
    float* acc = wsf;
    unsigned int* cnt = (unsigned int*)wsf + 4;
    const int bid = blockIdx.x;
    const int t   = threadIdx.x;

    float v = 0.0f;
    int accIdx;
    if (bid < 576) {
        int base;
        if (bid < 256)      { accIdx = 0; base = DIR_PF  + bid * 256;         }
        else if (bid < 512) { accIdx = 1; base = DIR_FP  + (bid - 256) * 256; }
        else                { accIdx = 2; base = DIR_FID + (bid - 512) * 256; }
        const int i = OFF_SEG + base + t;
        float m = wsf[i];
        for (int sg = 1; sg < ysplit; ++sg) m = fminf(m, wsf[sg * SEG + i]);
        v = sqrtf(fmaxf(m, 1e-12f));
    } else {
        accIdx = 3;
#pragma unroll
        for (int k = 0; k < BATCH * DLAT / 256; ++k) {
            const int i = k * 256 + t;
            const float m = mu[i];
            const float l = logvar[i];
            v += -0.5f * (1.0f + l - m * m - expf(l));
        }
    }

    v = blockReduceSum(v);
    if (t == 0) {
        atomicAdd(&acc[accIdx], v);
        __threadfence();
        const unsigned int done = atomicAdd(cnt, 1u);
        if (done == NRED_BLOCKS - 1) {
            const float s_pf  = atomicAdd(&acc[0], 0.0f);
            const float s_fp  = atomicAdd(&acc[1], 0.0f);
            const float s_fid = atomicAdd(&acc[2], 0.0f);
            const float s_kl  = atomicAdd(&acc[3], 0.0f);
            const float cd  = 0.5f * (s_pf / (float)(BATCH * NPTS) +
                                      s_fp / (float)(BATCH * NPTS));
            const float fid = s_fid / (float)(BATCH * PPTS);
            const float kl  = s_kl / (float)BATCH;
            out[0] = cd + 0.01f * kl + 0.5f * fid;  // CD_W=1, BETA=0.01, FID_W=0.5
            out[1] = cd;
            out[2] = kl;
            out[3] = fid;
        }
    }
}

// ---------------------------------------------------------------- launch
extern "C" void kernel_launch(void* const* d_in, const int* in_sizes, int n_in,
                              void* d_out, int out_size, void* d_ws, size_t ws_size,
                              hipStream_t stream) {
    const float* pred    = (const float*)d_in[0];
    const float* full    = (const float*)d_in[1];
    const float* partial = (const float*)d_in[2];
    const float* mu      = (const float*)d_in[3];
    const float* logvar  = (const float*)d_in[4];
    float* out = (float*)d_out;
    float* wsf = (float*)d_ws;

    // ysplit chosen from ws capacity (deterministic: ws_size fixed across calls)
    const size_t need4 = (size_t)(OFF_SEG + 4 * SEG) * 4;
    const int ysplit = (ws_size >= need4) ? 4 : 2;

    // 1. MFMA min-distance pass (block 0 also zeroes acc+counter)
    minpass_kernel<<<8 * 36 * ysplit, 256, 0, stream>>>(pred, full, partial, wsf, ysplit);

    // 2. all reductions + finalize in one dispatch
    reduce_finalize_kernel<<<NRED_BLOCKS, 256, 0, stream>>>(wsf, mu, logvar, out, ysplit);
}

// Round 2
// 103.240 us; speedup vs baseline: 1.1185x; 1.1185x over previous
//
#include <hip/hip_runtime.h>
#include <math.h>

// Problem sizes (fixed by reference setup_inputs)
#define BATCH 8
#define NPTS  8192   // pred/full points per batch
#define PPTS  2048   // partial points per batch
#define DLAT  512    // latent dim

// Split of the y axis across blocks. Each block stages its WHOLE y range
// (CHUNK = NPTS/YSPLIT points) into LDS once -> exactly ONE mid-kernel
// barrier, then an uninterrupted MFMA+min loop. Cross-split combine is a
// device-scope atomicMin on the uint bit pattern (all values >= 0), so only
// ONE workspace segment is needed regardless of YSPLIT.
#define YSPLIT 8
#define CHUNK  (NPTS / YSPLIT)   // 1024 y points per block, staged once (32 KB)
#define XBLK   512               // x points per block (4 waves x 4 col-groups)

typedef __attribute__((ext_vector_type(8)))  short short8;    // 8 bf16 (4 VGPR)
typedef __attribute__((ext_vector_type(16))) float floatx16;  // MFMA 32x32 C/D

// Workspace (float elements):
//   [0..4)    acc: sum_pf, sum_fp, sum_fid, sum_kl   (zeroed by minpass blk 0)
//   [4]       uint completion counter                 (zeroed by minpass blk 0)
//   [8..)     ONE segment of min-d^2 (pf | fp | fid), initialized to ~3.4e38
//             by hipMemsetAsync(0x7F), combined via atomicMin (uint order ==
//             float order for non-negative floats).
#define SEG      (2 * BATCH * NPTS + BATCH * PPTS)   // 147456 floats (~0.6 MB)
#define DIR_PF   0
#define DIR_FP   (BATCH * NPTS)
#define DIR_FID  (2 * BATCH * NPTS)
#define OFF_SEG  8

__device__ __forceinline__ unsigned short f2bf(float f) {  // RNE float->bf16
    unsigned int u = __float_as_uint(f);
    return (unsigned short)((u + 0x7FFFu + ((u >> 16) & 1u)) >> 16);
}
__device__ __forceinline__ float bf2f(unsigned short s) {
    return __uint_as_float(((unsigned int)s) << 16);
}

// min over 16 accumulator regs (16 rows of this lane's column) + carry-in.
// Plain fminf tree (R1 post-mortem: forced v_min3 asm was neutral-to-harmful;
// VALUBusy includes MFMA cycles, the min tree was never the bottleneck).
__device__ __forceinline__ float min16(floatx16 d, float prev) {
    float a0 = fminf(fminf(d[0],  d[1]),  d[2]);
    float a1 = fminf(fminf(d[3],  d[4]),  d[5]);
    float a2 = fminf(fminf(d[6],  d[7]),  d[8]);
    float a3 = fminf(fminf(d[9],  d[10]), d[11]);
    float a4 = fminf(fminf(d[12], d[13]), d[14]);
    float b0 = fminf(fminf(a0, a1), a2);
    float b1 = fminf(fminf(a3, a4), d[15]);
    return fminf(fminf(b0, b1), prev);
}

// Encode one y point + its norm into two uint4 k-half records.
__device__ __forceinline__ void encodeY(float y0, float y1, float y2,
                                        uint4* r0, uint4* r1) {
    const unsigned short h0 = f2bf(y0), h1 = f2bf(y1), h2 = f2bf(y2);
    const unsigned short l0 = f2bf(y0 - bf2f(h0));
    const unsigned short l1 = f2bf(y1 - bf2f(h1));
    const unsigned short l2 = f2bf(y2 - bf2f(h2));
    const float yn = fmaf(y0, y0, fmaf(y1, y1, y2 * y2));
    const unsigned short nh = f2bf(yn);
    const unsigned short nl = f2bf(yn - bf2f(nh));
    r0->x = (unsigned int)h0 | ((unsigned int)h1 << 16);  // k0,k1: yh.x,yh.y
    r0->y = (unsigned int)h2 | ((unsigned int)l0 << 16);  // k2,k3: yh.z,yl.x
    r0->z = (unsigned int)l1 | ((unsigned int)l2 << 16);  // k4,k5: yl.y,yl.z
    r0->w = (unsigned int)h0 | ((unsigned int)h1 << 16);  // k6,k7: yh.x,yh.y
    r1->x = (unsigned int)h2 | ((unsigned int)nh << 16);  // k8,k9: yh.z,yn_h
    r1->y = (unsigned int)nl;                             // k10, k11=0
    r1->z = 0u; r1->w = 0u;
}

// ---------------------------------------------------------------- min pass
// K-slot scheme (11 of 16 used):
//   A(y): k0-2 yh | k3-5 yl | k6-8 yh | k9 yn_h | k10 yn_l | rest 0
//   B(x): k0-2 -2xh | k3-5 -2xh | k6-8 -2xl | k9 1 | k10 1 | rest 0
//   => T = |y|^2 - 2 x.y (split residual ~1e-4); |x|^2 added post-min in fp32.
// Block = 256 thr = 4 waves; block owns 512 x; wave owns 128 x (4 col-groups).
// Grid = 8 batches * 36 x-subblocks * YSPLIT = 2304 blocks (9/CU, 5 resident
// at 32 KB LDS). Stage-once => MFMA pipe never waits on a mid-loop barrier.
__global__ __launch_bounds__(256, 4) void minpass_kernel(
        const float* __restrict__ pred,
        const float* __restrict__ full,
        const float* __restrict__ partial,
        float* __restrict__ wsf) {
    const int bid = blockIdx.x;          // 8 batches * 36 subs * YSPLIT
    const int ys  = bid % YSPLIT;
    const int r   = bid / YSPLIT;
    const int b   = r / 36;
    const int s   = r % 36;

    const int t = threadIdx.x;

    // block 0 zeroes acc + counter for the reduce kernel (stream ordering)
    if (bid == 0) {
        if (t < 4) wsf[t] = 0.0f;
        if (t == 4) ((unsigned int*)wsf)[4] = 0u;
    }

    const float* xset; const float* yset; int minoff; int xbase;
    if (s < 16)      { xset = pred;    yset = full; xbase = b*NPTS + s*XBLK;
                       minoff = OFF_SEG + DIR_PF  + b*NPTS + s*XBLK; }
    else if (s < 32) { xset = full;    yset = pred; xbase = b*NPTS + (s-16)*XBLK;
                       minoff = OFF_SEG + DIR_FP  + b*NPTS + (s-16)*XBLK; }
    else             { xset = partial; yset = pred; xbase = b*PPTS + (s-32)*XBLK;
                       minoff = OFF_SEG + DIR_FID + b*PPTS + (s-32)*XBLK; }

    const int lane = t & 63;
    const int wid  = t >> 6;
    const int l31  = lane & 31;
    const int half = lane >> 5;

    __shared__ uint4 sY[2][CHUNK];   // y records [k-half][point]  (32 KB)

    // ---- per-lane x encode: lane needs x points xw + {0,32,64,96} + l31,
    // and only the k-half record matching its lane half. Encode in registers.
    const int xw = wid * 128;
    short8 bf0, bf1, bf2, bf3;
    float  xn0, xn1, xn2, xn3;
#pragma unroll
    for (int k = 0; k < 4; ++k) {
        const float* xp = xset + (size_t)(xbase + xw + k * 32 + l31) * 3;
        const float x0 = xp[0], x1 = xp[1], x2 = xp[2];
        const float m0 = -2.0f*x0, m1 = -2.0f*x1, m2 = -2.0f*x2;
        const unsigned short h0 = f2bf(m0), h1 = f2bf(m1), h2 = f2bf(m2);
        const unsigned short l0 = f2bf(m0 - bf2f(h0));
        const unsigned short l1 = f2bf(m1 - bf2f(h1));
        const unsigned short l2 = f2bf(m2 - bf2f(h2));
        const unsigned int one = 0x3F80u;
        uint4 r0, r1;
        r0.x = (unsigned int)h0 | ((unsigned int)h1 << 16);  // k0,k1
        r0.y = (unsigned int)h2 | ((unsigned int)h0 << 16);  // k2,k3
        r0.z = (unsigned int)h1 | ((unsigned int)h2 << 16);  // k4,k5
        r0.w = (unsigned int)l0 | ((unsigned int)l1 << 16);  // k6,k7
        r1.x = (unsigned int)l2 | (one << 16);               // k8,k9
        r1.y = one;                                          // k10,k11=0
        r1.z = 0u; r1.w = 0u;
        const uint4 rec = half ? r1 : r0;
        const short8 bfv = *(const short8*)&rec;
        const float  xnv = fmaf(x0, x0, fmaf(x1, x1, x2 * x2));
        if (k == 0) { bf0 = bfv; xn0 = xnv; }
        else if (k == 1) { bf1 = bfv; xn1 = xnv; }
        else if (k == 2) { bf2 = bfv; xn2 = xnv; }
        else { bf3 = bfv; xn3 = xnv; }
    }

    // ---- stage the block's ENTIRE y range once (4 points per thread)
    const float* ypts = yset + (size_t)(b * NPTS + ys * CHUNK) * 3;
    for (int i = t; i < CHUNK; i += 256) {
        const float* yp = ypts + (size_t)i * 3;
        uint4 r0, r1;
        encodeY(yp[0], yp[1], yp[2], &r0, &r1);
        sY[0][i] = r0; sY[1][i] = r1;
    }
    __syncthreads();   // the ONLY barrier

    const floatx16 zc = {0,0,0,0, 0,0,0,0, 0,0,0,0, 0,0,0,0};
    float cmin0 = 3.4e38f, cmin1 = 3.4e38f, cmin2 = 3.4e38f, cmin3 = 3.4e38f;

    const uint4* sYh = &sY[half][0];

#define JBODY()                                                                         \
    do {                                                                                \
        const floatx16 d0 = __builtin_amdgcn_mfma_f32_32x32x16_bf16(af, bf0, zc, 0, 0, 0); \
        const floatx16 d1 = __builtin_amdgcn_mfma_f32_32x32x16_bf16(af, bf1, zc, 0, 0, 0); \
        cmin0 = min16(d0, cmin0);                                                       \
        const floatx16 d2 = __builtin_amdgcn_mfma_f32_32x32x16_bf16(af, bf2, zc, 0, 0, 0); \
        cmin1 = min16(d1, cmin1);                                                       \
        const floatx16 d3 = __builtin_amdgcn_mfma_f32_32x32x16_bf16(af, bf3, zc, 0, 0, 0); \
        cmin2 = min16(d2, cmin2);                                                       \
        cmin3 = min16(d3, cmin3);                                                       \
    } while (0)

    short8 af = *(const short8*)&sYh[l31];
#pragma unroll 8
    for (int j = 0; j < CHUNK / 32 - 1; ++j) {
        const short8 afn = *(const short8*)&sYh[(j + 1) * 32 + l31];  // prefetch
        JBODY();
        af = afn;
    }
    JBODY();   // peeled last iteration (no prefetch)
#undef JBODY

    // merge the two lane-halves (same column, different row halves), add |x|^2;
    // combine across YSPLIT via atomicMin on the uint pattern (values >= 0).
    const float m0 = fminf(cmin0, __shfl_xor(cmin0, 32, 64));
    const float m1 = fminf(cmin1, __shfl_xor(cmin1, 32, 64));
    const float m2 = fminf(cmin2, __shfl_xor(cmin2, 32, 64));
    const float m3 = fminf(cmin3, __shfl_xor(cmin3, 32, 64));
    if (lane < 32) {
        unsigned int* seg = (unsigned int*)wsf;
        atomicMin(&seg[minoff + xw + l31],
                  __float_as_uint(fmaxf(m0 + xn0, 0.0f)));
        atomicMin(&seg[minoff + xw + 32 + l31],
                  __float_as_uint(fmaxf(m1 + xn1, 0.0f)));
        atomicMin(&seg[minoff + xw + 64 + l31],
                  __float_as_uint(fmaxf(m2 + xn2, 0.0f)));
        atomicMin(&seg[minoff + xw + 96 + l31],
                  __float_as_uint(fmaxf(m3 + xn3, 0.0f)));
    }
}

// ---------------------------------------------------------------- reductions
__device__ __forceinline__ float waveReduceSum(float v) {
#pragma unroll
    for (int o = 32; o > 0; o >>= 1) v += __shfl_down(v, o, 64);
    return v;
}

__device__ __forceinline__ float blockReduceSum(float v) {
    __shared__ float wsum[4];
    const int lane = threadIdx.x & 63;
    const int wid  = threadIdx.x >> 6;
    v = waveReduceSum(v);
    if (lane == 0) wsum[wid] = v;
    __syncthreads();
    if (wid == 0) {
        v = (lane < ((int)blockDim.x >> 6)) ? wsum[lane] : 0.0f;
        v = waveReduceSum(v);
    }
    return v;
}

// Blocks 0..63: pf (1024 slots each), 64..127: fp, 128..143: fid, 144: kl.
// (Round-0 structure — its summation order measured absmax 0.0.)
#define NRED_BLOCKS 145
__global__ __launch_bounds__(256) void reduce_finalize_kernel(
        float* __restrict__ wsf,
        const float* __restrict__ mu,
        const float* __restrict__ logvar,
        float* __restrict__ out) {
    float* acc = wsf;
    unsigned int* cnt = (unsigned int*)wsf + 4;
    const int bid = blockIdx.x;
    const int t   = threadIdx.x;

    float v = 0.0f;
    int accIdx;
    if (bid < 144) {
        int base;
        if (bid < 64)       { accIdx = 0; base = DIR_PF  + bid * 1024;         }
        else if (bid < 128) { accIdx = 1; base = DIR_FP  + (bid - 64) * 1024;  }
        else                { accIdx = 2; base = DIR_FID + (bid - 128) * 1024; }
#pragma unroll
        for (int k = 0; k < 4; ++k) {
            const int i = OFF_SEG + base + k * 256 + t;
            v += sqrtf(fmaxf(wsf[i], 1e-12f));
        }
    } else {
        accIdx = 3;
#pragma unroll
        for (int k = 0; k < BATCH * DLAT / 256; ++k) {
            const int i = k * 256 + t;
            const float m = mu[i];
            const float l = logvar[i];
            v += -0.5f * (1.0f + l - m * m - expf(l));
        }
    }

    v = blockReduceSum(v);
    if (t == 0) {
        atomicAdd(&acc[accIdx], v);
        __threadfence();
        const unsigned int done = atomicAdd(cnt, 1u);
        if (done == NRED_BLOCKS - 1) {
            const float s_pf  = atomicAdd(&acc[0], 0.0f);
            const float s_fp  = atomicAdd(&acc[1], 0.0f);
            const float s_fid = atomicAdd(&acc[2], 0.0f);
            const float s_kl  = atomicAdd(&acc[3], 0.0f);
            const float cd  = 0.5f * (s_pf / (float)(BATCH * NPTS) +
                                      s_fp / (float)(BATCH * NPTS));
            const float fid = s_fid / (float)(BATCH * PPTS);
            const float kl  = s_kl / (float)BATCH;
            out[0] = cd + 0.01f * kl + 0.5f * fid;  // CD_W=1, BETA=0.01, FID_W=0.5
            out[1] = cd;
            out[2] = kl;
            out[3] = fid;
        }
    }
}

// ---------------------------------------------------------------- launch
extern "C" void kernel_launch(void* const* d_in, const int* in_sizes, int n_in,
                              void* d_out, int out_size, void* d_ws, size_t ws_size,
                              hipStream_t stream) {
    const float* pred    = (const float*)d_in[0];
    const float* full    = (const float*)d_in[1];
    const float* partial = (const float*)d_in[2];
    const float* mu      = (const float*)d_in[3];
    const float* logvar  = (const float*)d_in[4];
    float* out = (float*)d_out;
    float* wsf = (float*)d_ws;

    // 0. init the single min segment to ~3.4e38 (byte 0x7F -> 0x7F7F7F7F).
    //    Stream-ordered, graph-capturable.
    hipMemsetAsync((char*)d_ws + (size_t)OFF_SEG * sizeof(float), 0x7F,
                   (size_t)SEG * sizeof(float), stream);

    // 1. MFMA min-distance pass (block 0 also zeroes acc+counter)
    minpass_kernel<<<8 * 36 * YSPLIT, 256, 0, stream>>>(pred, full, partial, wsf);

    // 2. all reductions + finalize in one dispatch
    reduce_finalize_kernel<<<NRED_BLOCKS, 256, 0, stream>>>(wsf, mu, logvar, out);
}